// Round 1
// baseline (351.427 us; speedup 1.0000x reference)
//
#include <hip/hip_runtime.h>
#include <hip/hip_bf16.h>

// Problem constants
#define B_ROWS 16384
#define OBS_D  512
#define H_D    1024
#define N_AG   9

typedef __attribute__((ext_vector_type(8))) short short8;
typedef __attribute__((ext_vector_type(4))) float floatx4;

__device__ __forceinline__ float bf_raw_to_f(short u) {
  unsigned v = ((unsigned)(unsigned short)u) << 16;
  union { unsigned u; float f; } c; c.u = v; return c.f;
}

__device__ __forceinline__ unsigned short f_to_bf_raw(float f) {
  union { float f; unsigned u; } c; c.f = f;
  unsigned u = c.u;
  u = u + 0x7FFF + ((u >> 16) & 1);   // round-to-nearest-even
  return (unsigned short)(u >> 16);
}

// ---------------------------------------------------------------------------
// Prep: fp32 -> bf16 cast (obs), vectorized 8 elems/thread
// ---------------------------------------------------------------------------
__global__ __launch_bounds__(256) void cvt_f32_bf16_vec(
    const float* __restrict__ in, unsigned short* __restrict__ out, int n) {
  int i = (blockIdx.x * 256 + threadIdx.x) * 8;
  if (i >= n) return;
  float4 a = *(const float4*)(in + i);
  float4 b = *(const float4*)(in + i + 4);
  short8 o;
  o[0] = (short)f_to_bf_raw(a.x); o[1] = (short)f_to_bf_raw(a.y);
  o[2] = (short)f_to_bf_raw(a.z); o[3] = (short)f_to_bf_raw(a.w);
  o[4] = (short)f_to_bf_raw(b.x); o[5] = (short)f_to_bf_raw(b.y);
  o[6] = (short)f_to_bf_raw(b.z); o[7] = (short)f_to_bf_raw(b.w);
  *(short8*)(out + i) = o;
}

// ---------------------------------------------------------------------------
// Prep: transpose [K,N] fp32 -> [N,K] bf16 (LDS tile, padded)
// ---------------------------------------------------------------------------
__global__ __launch_bounds__(256) void transpose_w(
    const float* __restrict__ in, unsigned short* __restrict__ out, int K, int N) {
  __shared__ float t[32][33];
  const int k0 = blockIdx.x * 32;
  const int n0 = blockIdx.y * 32;
  const int tx = threadIdx.x & 31;
  const int ty = threadIdx.x >> 5;   // 0..7
#pragma unroll
  for (int i = ty; i < 32; i += 8)
    t[i][tx] = in[(size_t)(k0 + i) * N + n0 + tx];
  __syncthreads();
#pragma unroll
  for (int i = ty; i < 32; i += 8)
    out[(size_t)(n0 + i) * K + k0 + tx] = f_to_bf_raw(t[tx][i]);
}

// ---------------------------------------------------------------------------
// Prep: Wk1 [2048,1024]: out[n,k] = Wk1[k,n] + Wk1[k+1024,n]  (bf16 [1024,1024])
// concat([g,g]) @ Wk1 == g @ (Wk1_top + Wk1_bot)
// ---------------------------------------------------------------------------
__global__ __launch_bounds__(256) void wk1_sum_t(
    const float* __restrict__ in, unsigned short* __restrict__ out) {
  __shared__ float t[32][33];
  const int k0 = blockIdx.x * 32;
  const int n0 = blockIdx.y * 32;
  const int tx = threadIdx.x & 31;
  const int ty = threadIdx.x >> 5;
#pragma unroll
  for (int i = ty; i < 32; i += 8)
    t[i][tx] = in[(size_t)(k0 + i) * 1024 + n0 + tx]
             + in[(size_t)(k0 + i + 1024) * 1024 + n0 + tx];
  __syncthreads();
#pragma unroll
  for (int i = ty; i < 32; i += 8)
    out[(size_t)(n0 + i) * 1024 + k0 + tx] = f_to_bf_raw(t[tx][i]);
}

// ---------------------------------------------------------------------------
// GEMM: C[M,N] = relu(A[M,K] @ Bt[N,K]^T + bias), bf16 in/out, fp32 acc.
// m97 structure: 128x128 tile, BK=32, 4 waves x (4x4 16x16x32 MFMA),
// global_load_lds width=16 staging, 2-barrier K-loop.
// M,N,K all multiples of 128/32 here -> no bounds checks.
// ---------------------------------------------------------------------------
__global__ __launch_bounds__(256) void gemm_bias_relu(
    const unsigned short* __restrict__ A,
    const unsigned short* __restrict__ Bt,
    const float* __restrict__ bias,
    unsigned short* __restrict__ C,
    int M, int N, int K) {
  __shared__ __align__(16) unsigned short As[128 * 32];
  __shared__ __align__(16) unsigned short Bs[128 * 32];

  const int tid  = threadIdx.x;
  const int lane = tid & 63;
  const int wave = tid >> 6;
  const int m0 = blockIdx.x * 128;
  const int n0 = blockIdx.y * 128;
  const int wm = (wave & 1) * 64;
  const int wn = (wave >> 1) * 64;
  const int fr = lane & 15;   // frag row/col
  const int fq = lane >> 4;   // frag quad

  floatx4 acc[4][4];
#pragma unroll
  for (int i = 0; i < 4; ++i)
#pragma unroll
    for (int j = 0; j < 4; ++j) acc[i][j] = (floatx4){0.f, 0.f, 0.f, 0.f};

  const int srow  = lane >> 2;        // 0..15: row within 16-row chunk
  const int scolb = (lane & 3) * 16;  // byte col within 64B row segment
  const char* Abase = (const char*)(A + (size_t)m0 * K);
  const char* Bbase = (const char*)(Bt + (size_t)n0 * K);
  const size_t rowb = (size_t)K * 2;

  for (int k0 = 0; k0 < K; k0 += 32) {
#pragma unroll
    for (int j = 0; j < 2; ++j) {
      const int chunk = wave * 2 + j;          // 0..7: 16-row chunk of the tile
      const int r = chunk * 16 + srow;
      const char* ga = Abase + (size_t)r * rowb + (size_t)k0 * 2 + scolb;
      const char* gb = Bbase + (size_t)r * rowb + (size_t)k0 * 2 + scolb;
      // LDS dest must be wave-uniform base + lane*16 (contiguous lane order)
      char* la = (char*)As + chunk * 1024 + lane * 16;
      char* lb = (char*)Bs + chunk * 1024 + lane * 16;
      __builtin_amdgcn_global_load_lds((const __attribute__((address_space(1))) void*)ga,
                                       (__attribute__((address_space(3))) void*)la, 16, 0, 0);
      __builtin_amdgcn_global_load_lds((const __attribute__((address_space(1))) void*)gb,
                                       (__attribute__((address_space(3))) void*)lb, 16, 0, 0);
    }
    __syncthreads();   // compiler emits s_waitcnt vmcnt(0) before s_barrier

    short8 af[4], bfr[4];
#pragma unroll
    for (int mi = 0; mi < 4; ++mi)
      af[mi] = *(const short8*)((const char*)As + (wm + mi * 16 + fr) * 64 + fq * 16);
#pragma unroll
    for (int ni = 0; ni < 4; ++ni)
      bfr[ni] = *(const short8*)((const char*)Bs + (wn + ni * 16 + fr) * 64 + fq * 16);
#pragma unroll
    for (int mi = 0; mi < 4; ++mi)
#pragma unroll
      for (int ni = 0; ni < 4; ++ni)
        acc[mi][ni] = __builtin_amdgcn_mfma_f32_16x16x32_bf16(af[mi], bfr[ni], acc[mi][ni], 0, 0, 0);
    __syncthreads();
  }

  // Epilogue: C/D layout col=lane&15, row=(lane>>4)*4+reg
#pragma unroll
  for (int ni = 0; ni < 4; ++ni) {
    const int gn = n0 + wn + ni * 16 + fr;
    const float bv = bias[gn];
#pragma unroll
    for (int mi = 0; mi < 4; ++mi) {
#pragma unroll
      for (int r = 0; r < 4; ++r) {
        const int gm = m0 + wm + mi * 16 + fq * 4 + r;
        float v = acc[mi][ni][r] + bv;
        v = v > 0.f ? v : 0.f;
        C[(size_t)gm * N + gn] = f_to_bf_raw(v);
      }
    }
  }
}

// ---------------------------------------------------------------------------
// Final heads: per row, dot(covh, Wc2), dot(trkh, Wt2), dot(cooph, Wk2),
// + bias, sigmoid, broadcast to 9 agents. One wave per row.
// out layout: [coverage B*9][tracking B*9][cooperation B*9]
// ---------------------------------------------------------------------------
__global__ __launch_bounds__(256) void heads_final(
    const unsigned short* __restrict__ covh,
    const unsigned short* __restrict__ trkh,
    const unsigned short* __restrict__ cooph,
    const float* __restrict__ Wc2, const float* __restrict__ bc2,
    const float* __restrict__ Wt2, const float* __restrict__ bt2,
    const float* __restrict__ Wk2, const float* __restrict__ bk2,
    float* __restrict__ out) {
  const int lane = threadIdx.x & 63;
  const int row  = blockIdx.x * 4 + (threadIdx.x >> 6);

  float sc = 0.f, st = 0.f, sk = 0.f;
  {
    short8 v = *(const short8*)(covh + (size_t)row * 512 + lane * 8);
#pragma unroll
    for (int j = 0; j < 8; ++j) sc += bf_raw_to_f(v[j]) * Wc2[lane * 8 + j];
  }
  {
    short8 v = *(const short8*)(trkh + (size_t)row * 512 + lane * 8);
#pragma unroll
    for (int j = 0; j < 8; ++j) st += bf_raw_to_f(v[j]) * Wt2[lane * 8 + j];
  }
  {
    short8 v0 = *(const short8*)(cooph + (size_t)row * 1024 + lane * 16);
    short8 v1 = *(const short8*)(cooph + (size_t)row * 1024 + lane * 16 + 8);
#pragma unroll
    for (int j = 0; j < 8; ++j) sk += bf_raw_to_f(v0[j]) * Wk2[lane * 16 + j];
#pragma unroll
    for (int j = 0; j < 8; ++j) sk += bf_raw_to_f(v1[j]) * Wk2[lane * 16 + 8 + j];
  }
#pragma unroll
  for (int off = 32; off > 0; off >>= 1) {
    sc += __shfl_down(sc, off);
    st += __shfl_down(st, off);
    sk += __shfl_down(sk, off);
  }
  if (lane == 0) {
    const float cv = 1.f / (1.f + expf(-(sc + bc2[0])));
    const float tv = 1.f / (1.f + expf(-(st + bt2[0])));
    const float kv = 1.f / (1.f + expf(-(sk + bk2[0])));
    float* o0 = out + (size_t)row * N_AG;
    float* o1 = out + (size_t)(B_ROWS + row) * N_AG;
    float* o2 = out + (size_t)(2 * B_ROWS + row) * N_AG;
#pragma unroll
    for (int j = 0; j < N_AG; ++j) { o0[j] = cv; o1[j] = tv; o2[j] = kv; }
  }
}

// ---------------------------------------------------------------------------
extern "C" void kernel_launch(void* const* d_in, const int* in_sizes, int n_in,
                              void* d_out, int out_size, void* d_ws, size_t ws_size,
                              hipStream_t stream) {
  const float* obs = (const float*)d_in[0];
  // d_in[1] agent_positions: unused (outputs don't depend on it)
  const float* W1  = (const float*)d_in[2];
  const float* b1  = (const float*)d_in[3];
  const float* W2  = (const float*)d_in[4];
  const float* b2  = (const float*)d_in[5];
  const float* Wc1 = (const float*)d_in[6];
  const float* bc1 = (const float*)d_in[7];
  const float* Wc2 = (const float*)d_in[8];
  const float* bc2 = (const float*)d_in[9];
  const float* Wt1 = (const float*)d_in[10];
  const float* bt1 = (const float*)d_in[11];
  const float* Wt2 = (const float*)d_in[12];
  const float* bt2 = (const float*)d_in[13];
  const float* Wk1 = (const float*)d_in[14];
  const float* bk1 = (const float*)d_in[15];
  const float* Wk2 = (const float*)d_in[16];
  const float* bk2 = (const float*)d_in[17];
  float* out = (float*)d_out;

  // Workspace layout (bytes), total ~103 MB, with buffer reuse:
  char* ws = (char*)d_ws;
  unsigned short* obs_bf = (unsigned short*)(ws + 0);         // 16 MB (reused as COVH)
  unsigned short* W1T    = (unsigned short*)(ws + 16777216);  // 1 MB [1024,512]
  unsigned short* W2T    = (unsigned short*)(ws + 17825792);  // 2 MB [1024,1024]
  unsigned short* WC1T   = (unsigned short*)(ws + 19922944);  // 1 MB [512,1024]
  unsigned short* WT1T   = (unsigned short*)(ws + 20971520);  // 1 MB [512,1024]
  unsigned short* WK1S   = (unsigned short*)(ws + 22020096);  // 2 MB [1024,1024]
  unsigned short* G1     = (unsigned short*)(ws + 24117248);  // 32 MB (reused as COOPH)
  unsigned short* G      = (unsigned short*)(ws + 57671680);  // 32 MB
  unsigned short* TRKH   = (unsigned short*)(ws + 91226112);  // 16 MB
  unsigned short* COVH   = obs_bf;   // obs dead after GEMM1
  unsigned short* COOPH  = G1;       // g1 dead after GEMM2

  // Prep: casts / transposes / Wk1 fold
  cvt_f32_bf16_vec<<<4096, 256, 0, stream>>>(obs, obs_bf, B_ROWS * OBS_D);
  transpose_w<<<dim3(16, 32), 256, 0, stream>>>(W1, W1T, 512, 1024);
  transpose_w<<<dim3(32, 32), 256, 0, stream>>>(W2, W2T, 1024, 1024);
  transpose_w<<<dim3(32, 16), 256, 0, stream>>>(Wc1, WC1T, 1024, 512);
  transpose_w<<<dim3(32, 16), 256, 0, stream>>>(Wt1, WT1T, 1024, 512);
  wk1_sum_t<<<dim3(32, 32), 256, 0, stream>>>(Wk1, WK1S);

  // Trunk + heads (all MFMA GEMMs, fused bias+relu)
  gemm_bias_relu<<<dim3(128, 8), 256, 0, stream>>>(obs_bf, W1T, b1, G1, B_ROWS, 1024, 512);
  gemm_bias_relu<<<dim3(128, 8), 256, 0, stream>>>(G1, W2T, b2, G, B_ROWS, 1024, 1024);
  gemm_bias_relu<<<dim3(128, 4), 256, 0, stream>>>(G, WC1T, bc1, COVH, B_ROWS, 512, 1024);
  gemm_bias_relu<<<dim3(128, 4), 256, 0, stream>>>(G, WT1T, bt1, TRKH, B_ROWS, 512, 1024);
  gemm_bias_relu<<<dim3(128, 8), 256, 0, stream>>>(G, WK1S, bk1, COOPH, B_ROWS, 1024, 1024);

  // Final tiny GEMVs + sigmoid + broadcast
  heads_final<<<B_ROWS / 4, 256, 0, stream>>>(COVH, TRKH, COOPH,
                                              Wc2, bc2, Wt2, bt2, Wk2, bk2, out);
}

// Round 2
// 313.731 us; speedup vs baseline: 1.1202x; 1.1202x over previous
//
#include <hip/hip_runtime.h>
#include <hip/hip_bf16.h>

// Problem constants
#define B_ROWS 16384
#define OBS_D  512
#define H_D    1024
#define N_AG   9

typedef __attribute__((ext_vector_type(8))) short short8;
typedef __attribute__((ext_vector_type(4))) float floatx4;

__device__ __forceinline__ float bf_raw_to_f(short u) {
  unsigned v = ((unsigned)(unsigned short)u) << 16;
  union { unsigned u; float f; } c; c.u = v; return c.f;
}

__device__ __forceinline__ unsigned short f_to_bf_raw(float f) {
  union { float f; unsigned u; } c; c.f = f;
  unsigned u = c.u;
  u = u + 0x7FFF + ((u >> 16) & 1);   // round-to-nearest-even
  return (unsigned short)(u >> 16);
}

// ---------------------------------------------------------------------------
// Zero-init fp32 buffer (sums accumulator; ws is poisoned 0xAA each call)
// ---------------------------------------------------------------------------
__global__ __launch_bounds__(256) void zero_f(float* __restrict__ p, int n) {
  int i = blockIdx.x * 256 + threadIdx.x;
  if (i < n) p[i] = 0.f;
}

// ---------------------------------------------------------------------------
// Prep: fp32 -> bf16 cast (obs), vectorized 8 elems/thread
// ---------------------------------------------------------------------------
__global__ __launch_bounds__(256) void cvt_f32_bf16_vec(
    const float* __restrict__ in, unsigned short* __restrict__ out, int n) {
  int i = (blockIdx.x * 256 + threadIdx.x) * 8;
  if (i >= n) return;
  float4 a = *(const float4*)(in + i);
  float4 b = *(const float4*)(in + i + 4);
  short8 o;
  o[0] = (short)f_to_bf_raw(a.x); o[1] = (short)f_to_bf_raw(a.y);
  o[2] = (short)f_to_bf_raw(a.z); o[3] = (short)f_to_bf_raw(a.w);
  o[4] = (short)f_to_bf_raw(b.x); o[5] = (short)f_to_bf_raw(b.y);
  o[6] = (short)f_to_bf_raw(b.z); o[7] = (short)f_to_bf_raw(b.w);
  *(short8*)(out + i) = o;
}

// ---------------------------------------------------------------------------
// Prep: transpose [K,N] fp32 -> [N,K] bf16 (LDS tile, padded)
// ---------------------------------------------------------------------------
__global__ __launch_bounds__(256) void transpose_w(
    const float* __restrict__ in, unsigned short* __restrict__ out, int K, int N) {
  __shared__ float t[32][33];
  const int k0 = blockIdx.x * 32;
  const int n0 = blockIdx.y * 32;
  const int tx = threadIdx.x & 31;
  const int ty = threadIdx.x >> 5;   // 0..7
#pragma unroll
  for (int i = ty; i < 32; i += 8)
    t[i][tx] = in[(size_t)(k0 + i) * N + n0 + tx];
  __syncthreads();
#pragma unroll
  for (int i = ty; i < 32; i += 8)
    out[(size_t)(n0 + i) * K + k0 + tx] = f_to_bf_raw(t[tx][i]);
}

// ---------------------------------------------------------------------------
// Prep: fused heads weight matrix WH[2048,1024] bf16 (transposed, [n][k]):
//   n <  512 : Wc1[k][n]
//   n < 1024 : Wt1[k][n-512]
//   else     : Wk1[k][n-1024] + Wk1[k+1024][n-1024]   (concat([g,g])@Wk1 fold)
// ---------------------------------------------------------------------------
__global__ __launch_bounds__(256) void prep_heads_w(
    const float* __restrict__ Wc1, const float* __restrict__ Wt1,
    const float* __restrict__ Wk1, unsigned short* __restrict__ WH) {
  __shared__ float t[32][33];
  const int k0 = blockIdx.x * 32;   // 0..992
  const int n0 = blockIdx.y * 32;   // 0..2016, region-uniform per block
  const int tx = threadIdx.x & 31;
  const int ty = threadIdx.x >> 5;
#pragma unroll
  for (int i = ty; i < 32; i += 8) {
    const int n = n0 + tx;
    float v;
    if (n0 < 512)
      v = Wc1[(size_t)(k0 + i) * 512 + n];
    else if (n0 < 1024)
      v = Wt1[(size_t)(k0 + i) * 512 + (n - 512)];
    else
      v = Wk1[(size_t)(k0 + i) * 1024 + (n - 1024)]
        + Wk1[(size_t)(k0 + i + 1024) * 1024 + (n - 1024)];
    t[i][tx] = v;
  }
  __syncthreads();
#pragma unroll
  for (int i = ty; i < 32; i += 8)
    WH[(size_t)(n0 + i) * 1024 + k0 + tx] = f_to_bf_raw(t[tx][i]);
}

// ---------------------------------------------------------------------------
// Prep: concat head biases [bc1|bt1|bk1] -> bias2048, and second-layer
// weights [Wc2|Wt2|Wk2] -> w2cat (both fp32, length 2048)
// ---------------------------------------------------------------------------
__global__ __launch_bounds__(256) void prep_heads_vec(
    const float* __restrict__ bc1, const float* __restrict__ bt1,
    const float* __restrict__ bk1, const float* __restrict__ Wc2,
    const float* __restrict__ Wt2, const float* __restrict__ Wk2,
    float* __restrict__ bias2048, float* __restrict__ w2cat) {
  int n = blockIdx.x * 256 + threadIdx.x;
  if (n >= 2048) return;
  float b, w;
  if (n < 512)       { b = bc1[n];        w = Wc2[n]; }
  else if (n < 1024) { b = bt1[n - 512];  w = Wt2[n - 512]; }
  else               { b = bk1[n - 1024]; w = Wk2[n - 1024]; }
  bias2048[n] = b;
  w2cat[n] = w;
}

// ---------------------------------------------------------------------------
// GEMM: C[M,N] = relu(A[M,K] @ Bt[N,K]^T + bias), bf16 in/out, fp32 acc.
// m97 structure: 128x128 tile, BK=32, 4 waves x (4x4 16x16x32 MFMA),
// global_load_lds width=16 staging, 2-barrier K-loop.
// ---------------------------------------------------------------------------
__global__ __launch_bounds__(256) void gemm_bias_relu(
    const unsigned short* __restrict__ A,
    const unsigned short* __restrict__ Bt,
    const float* __restrict__ bias,
    unsigned short* __restrict__ C,
    int M, int N, int K) {
  __shared__ __align__(16) unsigned short As[128 * 32];
  __shared__ __align__(16) unsigned short Bs[128 * 32];

  const int tid  = threadIdx.x;
  const int lane = tid & 63;
  const int wave = tid >> 6;
  const int m0 = blockIdx.x * 128;
  const int n0 = blockIdx.y * 128;
  const int wm = (wave & 1) * 64;
  const int wn = (wave >> 1) * 64;
  const int fr = lane & 15;
  const int fq = lane >> 4;

  floatx4 acc[4][4];
#pragma unroll
  for (int i = 0; i < 4; ++i)
#pragma unroll
    for (int j = 0; j < 4; ++j) acc[i][j] = (floatx4){0.f, 0.f, 0.f, 0.f};

  const int srow  = lane >> 2;
  const int scolb = (lane & 3) * 16;
  const char* Abase = (const char*)(A + (size_t)m0 * K);
  const char* Bbase = (const char*)(Bt + (size_t)n0 * K);
  const size_t rowb = (size_t)K * 2;

  for (int k0 = 0; k0 < K; k0 += 32) {
#pragma unroll
    for (int j = 0; j < 2; ++j) {
      const int chunk = wave * 2 + j;
      const int r = chunk * 16 + srow;
      const char* ga = Abase + (size_t)r * rowb + (size_t)k0 * 2 + scolb;
      const char* gb = Bbase + (size_t)r * rowb + (size_t)k0 * 2 + scolb;
      char* la = (char*)As + chunk * 1024 + lane * 16;
      char* lb = (char*)Bs + chunk * 1024 + lane * 16;
      __builtin_amdgcn_global_load_lds((const __attribute__((address_space(1))) void*)ga,
                                       (__attribute__((address_space(3))) void*)la, 16, 0, 0);
      __builtin_amdgcn_global_load_lds((const __attribute__((address_space(1))) void*)gb,
                                       (__attribute__((address_space(3))) void*)lb, 16, 0, 0);
    }
    __syncthreads();

    short8 af[4], bfr[4];
#pragma unroll
    for (int mi = 0; mi < 4; ++mi)
      af[mi] = *(const short8*)((const char*)As + (wm + mi * 16 + fr) * 64 + fq * 16);
#pragma unroll
    for (int ni = 0; ni < 4; ++ni)
      bfr[ni] = *(const short8*)((const char*)Bs + (wn + ni * 16 + fr) * 64 + fq * 16);
#pragma unroll
    for (int mi = 0; mi < 4; ++mi)
#pragma unroll
      for (int ni = 0; ni < 4; ++ni)
        acc[mi][ni] = __builtin_amdgcn_mfma_f32_16x16x32_bf16(af[mi], bfr[ni], acc[mi][ni], 0, 0, 0);
    __syncthreads();
  }

#pragma unroll
  for (int ni = 0; ni < 4; ++ni) {
    const int gn = n0 + wn + ni * 16 + fr;
    const float bv = bias[gn];
#pragma unroll
    for (int mi = 0; mi < 4; ++mi) {
#pragma unroll
      for (int r = 0; r < 4; ++r) {
        const int gm = m0 + wm + mi * 16 + fq * 4 + r;
        float v = acc[mi][ni][r] + bv;
        v = v > 0.f ? v : 0.f;
        C[(size_t)gm * N + gn] = f_to_bf_raw(v);
      }
    }
  }
}

// ---------------------------------------------------------------------------
// Fused heads GEMM: H = relu(G @ WH^T + bias2048) computed in registers,
// immediately dotted with w2cat per-column and reduced into sums[B,3]
// (region 0=coverage cols 0..511, 1=tracking 512..1023, 2=coop 1024..2047).
// Never materializes the 64 MB head activations.
// ---------------------------------------------------------------------------
__global__ __launch_bounds__(256) void gemm_heads_fused(
    const unsigned short* __restrict__ A,    // G [B,1024]
    const unsigned short* __restrict__ Bt,   // WH [2048,1024]
    const float* __restrict__ bias,          // bias2048
    const float* __restrict__ w2,            // w2cat
    float* __restrict__ sums,                // [B,3] fp32, pre-zeroed
    int M, int N, int K) {
  __shared__ __align__(16) unsigned short As[128 * 32];
  __shared__ __align__(16) unsigned short Bs[128 * 32];

  const int tid  = threadIdx.x;
  const int lane = tid & 63;
  const int wave = tid >> 6;
  const int m0 = blockIdx.x * 128;
  const int n0 = blockIdx.y * 128;
  const int wm = (wave & 1) * 64;
  const int wn = (wave >> 1) * 64;
  const int fr = lane & 15;
  const int fq = lane >> 4;

  floatx4 acc[4][4];
#pragma unroll
  for (int i = 0; i < 4; ++i)
#pragma unroll
    for (int j = 0; j < 4; ++j) acc[i][j] = (floatx4){0.f, 0.f, 0.f, 0.f};

  const int srow  = lane >> 2;
  const int scolb = (lane & 3) * 16;
  const char* Abase = (const char*)(A + (size_t)m0 * K);
  const char* Bbase = (const char*)(Bt + (size_t)n0 * K);
  const size_t rowb = (size_t)K * 2;

  for (int k0 = 0; k0 < K; k0 += 32) {
#pragma unroll
    for (int j = 0; j < 2; ++j) {
      const int chunk = wave * 2 + j;
      const int r = chunk * 16 + srow;
      const char* ga = Abase + (size_t)r * rowb + (size_t)k0 * 2 + scolb;
      const char* gb = Bbase + (size_t)r * rowb + (size_t)k0 * 2 + scolb;
      char* la = (char*)As + chunk * 1024 + lane * 16;
      char* lb = (char*)Bs + chunk * 1024 + lane * 16;
      __builtin_amdgcn_global_load_lds((const __attribute__((address_space(1))) void*)ga,
                                       (__attribute__((address_space(3))) void*)la, 16, 0, 0);
      __builtin_amdgcn_global_load_lds((const __attribute__((address_space(1))) void*)gb,
                                       (__attribute__((address_space(3))) void*)lb, 16, 0, 0);
    }
    __syncthreads();

    short8 af[4], bfr[4];
#pragma unroll
    for (int mi = 0; mi < 4; ++mi)
      af[mi] = *(const short8*)((const char*)As + (wm + mi * 16 + fr) * 64 + fq * 16);
#pragma unroll
    for (int ni = 0; ni < 4; ++ni)
      bfr[ni] = *(const short8*)((const char*)Bs + (wn + ni * 16 + fr) * 64 + fq * 16);
#pragma unroll
    for (int mi = 0; mi < 4; ++mi)
#pragma unroll
      for (int ni = 0; ni < 4; ++ni)
        acc[mi][ni] = __builtin_amdgcn_mfma_f32_16x16x32_bf16(af[mi], bfr[ni], acc[mi][ni], 0, 0, 0);
    __syncthreads();
  }

  // Epilogue: relu + per-column w2 weight + reduce over the 128 cols this
  // block owns, accumulate into sums[row, region]. Block's col range lies
  // entirely within one region (128 | 512).
  const int region = (n0 >= 1024) ? 2 : (n0 >> 9);
  float w2v[4], bv[4];
#pragma unroll
  for (int ni = 0; ni < 4; ++ni) {
    const int gn = n0 + wn + ni * 16 + fr;
    w2v[ni] = w2[gn];
    bv[ni]  = bias[gn];
  }
#pragma unroll
  for (int mi = 0; mi < 4; ++mi) {
#pragma unroll
    for (int r = 0; r < 4; ++r) {
      float p = 0.f;
#pragma unroll
      for (int ni = 0; ni < 4; ++ni) {
        float v = acc[mi][ni][r] + bv[ni];
        v = v > 0.f ? v : 0.f;
        p += v * w2v[ni];
      }
      // reduce across the 16 lanes (fr) that share this row
      p += __shfl_xor(p, 1);
      p += __shfl_xor(p, 2);
      p += __shfl_xor(p, 4);
      p += __shfl_xor(p, 8);
      if (fr == 0) {
        const int gm = m0 + wm + mi * 16 + fq * 4 + r;
        atomicAdd(&sums[gm * 3 + region], p);
      }
    }
  }
}

// ---------------------------------------------------------------------------
// Final: sigmoid(sums + bias) broadcast to out [3, B, 9]
// ---------------------------------------------------------------------------
__global__ __launch_bounds__(256) void final_out(
    const float* __restrict__ sums,
    const float* __restrict__ bc2, const float* __restrict__ bt2,
    const float* __restrict__ bk2, float* __restrict__ out) {
  int i = blockIdx.x * 256 + threadIdx.x;
  const int total = 3 * B_ROWS * N_AG;
  if (i >= total) return;
  const int region = i / (B_ROWS * N_AG);
  const int row = (i - region * (B_ROWS * N_AG)) / N_AG;
  const float b = (region == 0) ? bc2[0] : ((region == 1) ? bt2[0] : bk2[0]);
  const float s = sums[row * 3 + region] + b;
  out[i] = 1.f / (1.f + expf(-s));
}

// ---------------------------------------------------------------------------
extern "C" void kernel_launch(void* const* d_in, const int* in_sizes, int n_in,
                              void* d_out, int out_size, void* d_ws, size_t ws_size,
                              hipStream_t stream) {
  const float* obs = (const float*)d_in[0];
  // d_in[1] agent_positions: unused (outputs don't depend on it)
  const float* W1  = (const float*)d_in[2];
  const float* b1  = (const float*)d_in[3];
  const float* W2  = (const float*)d_in[4];
  const float* b2  = (const float*)d_in[5];
  const float* Wc1 = (const float*)d_in[6];
  const float* bc1 = (const float*)d_in[7];
  const float* Wc2 = (const float*)d_in[8];
  const float* bc2 = (const float*)d_in[9];
  const float* Wt1 = (const float*)d_in[10];
  const float* bt1 = (const float*)d_in[11];
  const float* Wt2 = (const float*)d_in[12];
  const float* bt2 = (const float*)d_in[13];
  const float* Wk1 = (const float*)d_in[14];
  const float* bk1 = (const float*)d_in[15];
  const float* Wk2 = (const float*)d_in[16];
  const float* bk2 = (const float*)d_in[17];
  float* out = (float*)d_out;

  // Workspace layout (bytes), ~91.5 MB total:
  char* ws = (char*)d_ws;
  unsigned short* obs_bf  = (unsigned short*)(ws + 0);         // 16 MB
  unsigned short* W1T     = (unsigned short*)(ws + 16777216);  // 1 MB  [1024,512]
  unsigned short* W2T     = (unsigned short*)(ws + 17825792);  // 2 MB  [1024,1024]
  unsigned short* WH      = (unsigned short*)(ws + 19922944);  // 4 MB  [2048,1024]
  float*          bias2048= (float*)(ws + 24117248);           // 8 KB
  float*          w2cat   = (float*)(ws + 24125440);           // 8 KB
  float*          SUMS    = (float*)(ws + 24133632);           // 192 KB [B,3]
  unsigned short* G1      = (unsigned short*)(ws + 24330240);  // 32 MB
  unsigned short* G       = (unsigned short*)(ws + 57884672);  // 32 MB

  // Prep
  zero_f<<<192, 256, 0, stream>>>(SUMS, B_ROWS * 3);
  cvt_f32_bf16_vec<<<4096, 256, 0, stream>>>(obs, obs_bf, B_ROWS * OBS_D);
  transpose_w<<<dim3(16, 32), 256, 0, stream>>>(W1, W1T, 512, 1024);
  transpose_w<<<dim3(32, 32), 256, 0, stream>>>(W2, W2T, 1024, 1024);
  prep_heads_w<<<dim3(32, 64), 256, 0, stream>>>(Wc1, Wt1, Wk1, WH);
  prep_heads_vec<<<8, 256, 0, stream>>>(bc1, bt1, bk1, Wc2, Wt2, Wk2, bias2048, w2cat);

  // Trunk
  gemm_bias_relu<<<dim3(128, 8), 256, 0, stream>>>(obs_bf, W1T, b1, G1, B_ROWS, 1024, 512);
  gemm_bias_relu<<<dim3(128, 8), 256, 0, stream>>>(G1, W2T, b2, G, B_ROWS, 1024, 1024);

  // All three heads in one fused GEMM + epilogue reduction
  gemm_heads_fused<<<dim3(128, 16), 256, 0, stream>>>(G, WH, bias2048, w2cat, SUMS,
                                                      B_ROWS, 2048, 1024);

  // Sigmoid + broadcast
  final_out<<<1728, 256, 0, stream>>>(SUMS, bc2, bt2, bk2, out);
}